// Round 10
// baseline (128.492 us; speedup 1.0000x reference)
//
#include <hip/hip_runtime.h>

// Pink-noise 6-pole IIR — warmup-tile parallel, ONE kernel, zero inter-block deps.
//
// Key fact: the slowest pole is 0.99886, so A^8192 = 8.7e-5 — the filter
// forgets its history in a few thousand samples. Each block computes one
// 8192-sample output tile preceded by an 8192-sample warmup scanned from zero
// state. Truncation error <= ~1e-5 (tolerance 7.8e-3); tile 0 of each channel
// is EXACT (zero prefix = true zero init).
//
// Round-9 lessons baked in:
//  - TWO LDS buffers (bufA warmup, bufB tile), ALL 8 float4 global loads
//    issued back-to-back at kernel start: ONE HBM round trip per block
//    (r9's buffer reuse put a second load round on the critical path).
//  - Phase-A and phase-B scans run back-to-back with NO barrier between
//    (separate swvA/swvB total arrays): 3 barriers total, and the two
//    independent scan dep-chains interleave to hide LDS latency.
//  - u-substitution: track u[p] = b[p]/C[p]; recurrence u = A*u + w is
//    6 fma/sample (was 12); output = dot(C,u) recovers b exactly (same
//    linear recurrence & multipliers — wave-scan math unchanged).
//  - Register prefetch lifetimes never cross a barrier (r8 spill lesson);
//    __launch_bounds__(512,2) = the r4-proven no-spill config. LDS 64.6 KB
//    -> 2 blocks/CU; cross-block TLP covers the load latency.

constexpr int kL = 65536;               // samples per channel
constexpr int kThr = 512;               // threads per block = 8 waves
constexpr int kWaves = kThr / 64;       // 8
constexpr int kT = 8192;                // output tile per block
constexpr int kW = 8192;                // warmup samples
constexpr int kPT = kT / kThr;          // 16 samples per thread per region
constexpr int kTilesPerCh = kL / kT;    // 8

// XOR swizzle: bank-balances both the 16-strided chunk reads and the linear
// float4 access patterns; involution; keeps float4 groups (bits 0-1) intact.
__device__ __forceinline__ int swz(int i) {
    return i ^ (((i >> 5) & 7) << 2);
}

__global__ __launch_bounds__(kThr, 2) void pink_tile(
    const float* __restrict__ white, float* __restrict__ pink)
{
    constexpr float A[6] = {0.99886f, 0.99332f, 0.969f, 0.8665f, 0.55f, -0.7616f};
    constexpr float C[6] = {0.0555179f, 0.0750759f, 0.153852f, 0.3104856f, 0.5329522f, -0.016898f};
    constexpr float B6G = 0.115926f, DIRECT = 0.5362f, OUTG = 0.11f;

    __shared__ __align__(16) float bufA[kW];     // 32 KiB warmup
    __shared__ __align__(16) float bufB[kT];     // 32 KiB output tile
    __shared__ float swvA[6][kWaves];
    __shared__ float swvB[6][kWaves];

    const int tid = threadIdx.x, lane = tid & 63, wave = tid >> 6;
    const int ch = blockIdx.x / kTilesPerCh;
    const int tI = blockIdx.x % kTilesPerCh;
    const size_t outBase = (size_t)ch * kL + (size_t)tI * kT;

    // ---- Stage BOTH buffers: one HBM round trip, coalesced float4 ----
    const float4* sB = (const float4*)(white + outBase);
    if (tI != 0) {
        const float4* sA = (const float4*)(white + outBase - kW);
        float4 a0 = sA[tid], a1 = sA[tid + kThr],
               a2 = sA[tid + 2*kThr], a3 = sA[tid + 3*kThr];
        float4 b0 = sB[tid], b1 = sB[tid + kThr],
               b2 = sB[tid + 2*kThr], b3 = sB[tid + 3*kThr];
        *(float4*)&bufA[swz(4*tid)]             = a0;
        *(float4*)&bufA[swz(4*(tid + kThr))]    = a1;
        *(float4*)&bufA[swz(4*(tid + 2*kThr))]  = a2;
        *(float4*)&bufA[swz(4*(tid + 3*kThr))]  = a3;
        *(float4*)&bufB[swz(4*tid)]             = b0;
        *(float4*)&bufB[swz(4*(tid + kThr))]    = b1;
        *(float4*)&bufB[swz(4*(tid + 2*kThr))]  = b2;
        *(float4*)&bufB[swz(4*(tid + 3*kThr))]  = b3;
    } else {
        float4 b0 = sB[tid], b1 = sB[tid + kThr],
               b2 = sB[tid + 2*kThr], b3 = sB[tid + 3*kThr];
        *(float4*)&bufB[swz(4*tid)]             = b0;
        *(float4*)&bufB[swz(4*(tid + kThr))]    = b1;
        *(float4*)&bufB[swz(4*(tid + 2*kThr))]  = b2;
        *(float4*)&bufB[swz(4*(tid + 3*kThr))]  = b3;
    }

    // Constants: mPT = A^16, pmL = (A^16)^lane, Mwv = (A^16)^64 = A^1024.
    // (Underflow to 0 for fast poles is numerically correct.)
    float mPT[6], pmL[6], Mwv[6];
    #pragma unroll
    for (int p = 0; p < 6; ++p) {
        float q = A[p];
        #pragma unroll
        for (int i = 0; i < 4; ++i) q *= q;          // A^16
        mPT[p] = q;
        float pm = 1.f, qq = q;
        #pragma unroll
        for (int b = 0; b < 6; ++b) { if ((lane >> b) & 1) pm *= qq; qq *= qq; }
        pmL[p] = pm;
        Mwv[p] = qq;                                  // (A^16)^64 = A^1024
    }
    __syncthreads();                 // both buffers staged  [barrier 1/3]

    // ---- Local scans (u-space: u = A*u + w), A and B interleaved ----
    float eA[6] = {0.f,0.f,0.f,0.f,0.f,0.f};
    float eB[6] = {0.f,0.f,0.f,0.f,0.f,0.f};
    #pragma unroll
    for (int kk = 0; kk < kPT / 4; ++kk) {
        float4 xA;
        if (tI != 0) xA = *(const float4*)&bufA[swz(kPT * tid + 4 * kk)];
        const float4 xB = *(const float4*)&bufB[swz(kPT * tid + 4 * kk)];
        const float* ap = &xA.x;
        const float* bp = &xB.x;
        #pragma unroll
        for (int j = 0; j < 4; ++j) {
            if (tI != 0) {
                const float wa = ap[j];
                #pragma unroll
                for (int p = 0; p < 6; ++p) eA[p] = fmaf(A[p], eA[p], wa);
            }
            const float wb = bp[j];
            #pragma unroll
            for (int p = 0; p < 6; ++p) eB[p] = fmaf(A[p], eB[p], wb);
        }
    }
    // Previous white for the b6 delay line (read before recompute overwrites).
    const float pwl = (tid == 0)
        ? ((tI != 0) ? bufA[swz(kW - 1)] : 0.f)
        : bufB[swz(kPT * tid - 1)];

    // ---- Wave affine scans, both regions in one pass (shared multipliers) --
    float mk[6];
    #pragma unroll
    for (int p = 0; p < 6; ++p) mk[p] = mPT[p];
    #pragma unroll
    for (int r = 0; r < 6; ++r) {
        const int off = 1 << r;
        float fA[6], fB[6];
        #pragma unroll
        for (int p = 0; p < 6; ++p) { fA[p] = __shfl_up(eA[p], off);
                                      fB[p] = __shfl_up(eB[p], off); }
        if (lane >= off) {
            #pragma unroll
            for (int p = 0; p < 6; ++p) { eA[p] = fmaf(mk[p], fA[p], eA[p]);
                                          eB[p] = fmaf(mk[p], fB[p], eB[p]); }
        }
        #pragma unroll
        for (int p = 0; p < 6; ++p) mk[p] *= mk[p];
    }
    float ex[6];
    #pragma unroll
    for (int p = 0; p < 6; ++p) {
        ex[p] = __shfl_up(eB[p], 1);
        if (lane == 0) ex[p] = 0.f;
    }
    if (lane == 63) {
        #pragma unroll
        for (int p = 0; p < 6; ++p) { swvA[p][wave] = eA[p];
                                      swvB[p][wave] = eB[p]; }
    }
    __syncthreads();                 // swvA + swvB ready  [barrier 2/3]

    // ---- Fold: R = warmup end state; X = R folded through prior B-waves ----
    float b[6];
    #pragma unroll
    for (int p = 0; p < 6; ++p) {
        float R = 0.f;
        if (tI != 0) {
            #pragma unroll
            for (int w2 = 0; w2 < kWaves; ++w2)
                R = fmaf(Mwv[p], R, swvA[p][w2]);
        }
        float X = R;
        #pragma unroll
        for (int w2 = 0; w2 < kWaves; ++w2)
            if (w2 < wave) X = fmaf(Mwv[p], X, swvB[p][w2]);
        b[p] = fmaf(pmL[p], X, ex[p]);
    }
    float b6 = B6G * pwl;

    // ---- Recompute with exact init; outputs overwrite own chunk in bufB ----
    #pragma unroll
    for (int kk = 0; kk < kPT / 4; ++kk) {
        const float4 x = *(const float4*)&bufB[swz(kPT * tid + 4 * kk)];
        const float* xp = &x.x;
        float4 o;
        float* op = &o.x;
        #pragma unroll
        for (int j = 0; j < 4; ++j) {
            const float ww = xp[j];
            #pragma unroll
            for (int p = 0; p < 6; ++p) b[p] = fmaf(A[p], b[p], ww);
            float t0 = C[0] * b[0];  t0 = fmaf(C[1], b[1], t0);
            float t1 = C[2] * b[2];  t1 = fmaf(C[3], b[3], t1);
            float t2 = C[4] * b[4];  t2 = fmaf(C[5], b[5], t2);
            const float sum = (t0 + t1) + (t2 + b6);
            op[j] = fmaf(DIRECT, ww, sum) * OUTG;
            b6 = B6G * ww;
        }
        *(float4*)&bufB[swz(kPT * tid + 4 * kk)] = o;
    }
    __syncthreads();                 // outputs staged  [barrier 3/3]

    // Coalesced store.
    float4* dst4 = (float4*)(pink + outBase);
    #pragma unroll
    for (int k = 0; k < 4; ++k)
        dst4[tid + k * kThr] = *(const float4*)&bufB[swz(4 * (tid + k * kThr))];
}

extern "C" void kernel_launch(void* const* d_in, const int* in_sizes, int n_in,
                              void* d_out, int out_size, void* d_ws, size_t ws_size,
                              hipStream_t stream) {
    const float* white = (const float*)d_in[0];
    float* pink = (float*)d_out;
    const int nCh = in_sizes[0] / kL;                 // 256 channels
    const int nBlk = nCh * kTilesPerCh;               // 2048 blocks

    hipLaunchKernelGGL(pink_tile, dim3(nBlk), dim3(kThr), 0, stream,
                       white, pink);
}

// Round 11
// 123.886 us; speedup vs baseline: 1.0372x; 1.0372x over previous
//
#include <hip/hip_runtime.h>

// Pink-noise 6-pole IIR — warmup-tile parallel, all-register, ONE barrier.
//
// Decomposition (proven r5-r10): slowest pole 0.99886 -> A^8192 = 8.7e-5, so
// each block computes one 8192-sample output tile from zero state preceded by
// an 8192-sample warmup. Truncation error ~1e-4 (passes at the harness
// tolerance since r5); tile 0 of each channel is EXACT.
//
// Round-10 lesson: the LDS staging machinery (32-64 KB buffers, transpose
// round-trips, 3-5 barriers, bank conflicts) IS the bottleneck — every
// variant lands 43-63 µs with both pipes <50%. This version eliminates the
// data LDS entirely: thread t directly loads its 16 CONTIGUOUS samples
// (4x float4, 64 B/lane — every byte of every cache line consumed; loads
// batched independent -> ONE wait, unlike r7's serial load-scan interleave).
// Register budget: the 4 float4s are reused for warmup then tile; u-space
// scan (u = A*u + w, 6 fma/sample); live set ~55 fits the <=64-VGPR bin ->
// __launch_bounds__(512,4) = 4 blocks/CU (32 waves/CU), zero bank conflicts,
// one __syncthreads for the 420-byte wave-total exchange.
//
// Occupancy model (r4/r5/r8/r9 evidence): wave slots quantize at VGPR
// 64/128/256; 3+ blocks of 8 waves requires <=64 regs. Spill tripwire:
// WRITE_SIZE > 66 MB next round => relax to (512,2).

constexpr int kL = 65536;               // samples per channel
constexpr int kThr = 512;               // threads per block = 8 waves
constexpr int kWaves = kThr / 64;       // 8
constexpr int kPT = 16;                 // contiguous samples per thread/region
constexpr int kT = kThr * kPT;          // 8192 output tile per block
constexpr int kW = 8192;                // warmup samples
constexpr int kTilesPerCh = kL / kT;    // 8

__global__ __launch_bounds__(kThr, 4) void pink_tile(
    const float* __restrict__ white, float* __restrict__ pink, int nBlk)
{
    constexpr float A[6] = {0.99886f, 0.99332f, 0.969f, 0.8665f, 0.55f, -0.7616f};
    constexpr float C[6] = {0.0555179f, 0.0750759f, 0.153852f, 0.3104856f, 0.5329522f, -0.016898f};
    constexpr float B6G = 0.115926f, DIRECT = 0.5362f, OUTG = 0.11f;

    __shared__ float swvA[6][kWaves];    // warmup wave totals (u-space)
    __shared__ float swvB[6][kWaves];    // tile wave totals (u-space)
    __shared__ float lastwB[kWaves];     // last tile sample per wave
    __shared__ float sLastWarm;          // last warmup sample of the block

    const int tid = threadIdx.x, lane = tid & 63, wave = tid >> 6;

    // XCD-aware swizzle (bijective: nBlk % 8 == 0): consecutive tiles of a
    // channel share an XCD L2, so tile t's data re-read as tile t+1's warmup
    // is an L2 hit.
    const int cpx = nBlk >> 3;
    const int vb = (blockIdx.x & 7) * cpx + (blockIdx.x >> 3);
    const int ch = vb / kTilesPerCh;
    const int tI = vb % kTilesPerCh;
    const size_t outBase = (size_t)ch * kL + (size_t)tI * kT;

    // Constants: mPT = A^16, pmL = (A^16)^lane, Mwv = (A^16)^64 = A^1024.
    // (Underflow to 0 for fast poles is numerically correct.)
    float mPT[6], pmL[6], Mwv[6];
    #pragma unroll
    for (int p = 0; p < 6; ++p) {
        float q = A[p];
        #pragma unroll
        for (int i = 0; i < 4; ++i) q *= q;          // A^16
        mPT[p] = q;
        float pm = 1.f, qq = q;
        #pragma unroll
        for (int b = 0; b < 6; ++b) { if ((lane >> b) & 1) pm *= qq; qq *= qq; }
        pmL[p] = pm;
        Mwv[p] = qq;                                  // (A^16)^64 = A^1024
    }

    // ---- Warmup region: 16 contiguous samples straight into registers ----
    float4 x0, x1, x2, x3;
    if (tI != 0) {
        const float* gA = white + outBase - kW + (size_t)kPT * tid;
        x0 = *(const float4*)(gA);
        x1 = *(const float4*)(gA + 4);
        x2 = *(const float4*)(gA + 8);
        x3 = *(const float4*)(gA + 12);
    } else {
        x0 = x1 = x2 = x3 = make_float4(0.f, 0.f, 0.f, 0.f);
    }

    float eA[6] = {0.f, 0.f, 0.f, 0.f, 0.f, 0.f};    // u-space: u = A*u + w
    {
        const float4 xs[1] = {};  (void)xs;
        #define SCAN4(V, E) { \
            const float* _p = &(V).x; \
            _Pragma("unroll") \
            for (int j = 0; j < 4; ++j) { \
                const float ww = _p[j]; \
                _Pragma("unroll") \
                for (int p = 0; p < 6; ++p) (E)[p] = fmaf(A[p], (E)[p], ww); \
            } }
        SCAN4(x0, eA) SCAN4(x1, eA) SCAN4(x2, eA) SCAN4(x3, eA)
        if (tid == kThr - 1) sLastWarm = x3.w;       // covered by the barrier
    }

    // ---- Tile region: reuse the same registers ----
    {
        const float* gB = white + outBase + (size_t)kPT * tid;
        x0 = *(const float4*)(gB);
        x1 = *(const float4*)(gB + 4);
        x2 = *(const float4*)(gB + 8);
        x3 = *(const float4*)(gB + 12);
    }
    float eB[6] = {0.f, 0.f, 0.f, 0.f, 0.f, 0.f};
    SCAN4(x0, eB) SCAN4(x1, eB) SCAN4(x2, eB) SCAN4(x3, eB)
    #undef SCAN4

    // ---- Shared wave affine scan (A and B interleaved, shared mk) ----
    float mk[6];
    #pragma unroll
    for (int p = 0; p < 6; ++p) mk[p] = mPT[p];
    #pragma unroll
    for (int r = 0; r < 6; ++r) {
        const int off = 1 << r;
        float fA[6], fB[6];
        #pragma unroll
        for (int p = 0; p < 6; ++p) { fA[p] = __shfl_up(eA[p], off);
                                      fB[p] = __shfl_up(eB[p], off); }
        if (lane >= off) {
            #pragma unroll
            for (int p = 0; p < 6; ++p) { eA[p] = fmaf(mk[p], fA[p], eA[p]);
                                          eB[p] = fmaf(mk[p], fB[p], eB[p]); }
        }
        #pragma unroll
        for (int p = 0; p < 6; ++p) mk[p] *= mk[p];
    }
    float ex[6];
    #pragma unroll
    for (int p = 0; p < 6; ++p) {
        ex[p] = __shfl_up(eB[p], 1);
        if (lane == 0) ex[p] = 0.f;
    }
    if (lane == 63) {
        #pragma unroll
        for (int p = 0; p < 6; ++p) { swvA[p][wave] = eA[p];
                                      swvB[p][wave] = eB[p]; }
        lastwB[wave] = x3.w;
    }
    __syncthreads();                 // the ONLY barrier

    // ---- Fold: warmup end state R, then prior tile waves, then lane span --
    float ub[6];
    #pragma unroll
    for (int p = 0; p < 6; ++p) {
        float R = 0.f;
        #pragma unroll
        for (int w2 = 0; w2 < kWaves; ++w2) R = fmaf(Mwv[p], R, swvA[p][w2]);
        float X = R;
        #pragma unroll
        for (int w2 = 0; w2 < kWaves; ++w2)
            if (w2 < wave) X = fmaf(Mwv[p], X, swvB[p][w2]);
        ub[p] = fmaf(pmL[p], X, ex[p]);
    }

    // Previous white sample for the b6 delay line.
    float pwl = __shfl_up(x3.w, 1);
    if (lane == 0) pwl = (wave == 0) ? sLastWarm : lastwB[wave - 1];
    float b6 = B6G * pwl;

    // ---- Recompute + store directly from registers (quarter at a time) ----
    float* dstF = pink + outBase + (size_t)kPT * tid;
    #define EMIT4(V, OFS) { \
        const float* _p = &(V).x; \
        float4 o; float* _o = &o.x; \
        _Pragma("unroll") \
        for (int j = 0; j < 4; ++j) { \
            const float ww = _p[j]; \
            _Pragma("unroll") \
            for (int p = 0; p < 6; ++p) ub[p] = fmaf(A[p], ub[p], ww); \
            float t0 = C[0] * ub[0];  t0 = fmaf(C[1], ub[1], t0); \
            float t1 = C[2] * ub[2];  t1 = fmaf(C[3], ub[3], t1); \
            float t2 = C[4] * ub[4];  t2 = fmaf(C[5], ub[5], t2); \
            const float sum = (t0 + t1) + (t2 + b6); \
            _o[j] = fmaf(DIRECT, ww, sum) * OUTG; \
            b6 = B6G * ww; \
        } \
        *(float4*)(dstF + (OFS)) = o; }
    EMIT4(x0, 0) EMIT4(x1, 4) EMIT4(x2, 8) EMIT4(x3, 12)
    #undef EMIT4
}

extern "C" void kernel_launch(void* const* d_in, const int* in_sizes, int n_in,
                              void* d_out, int out_size, void* d_ws, size_t ws_size,
                              hipStream_t stream) {
    const float* white = (const float*)d_in[0];
    float* pink = (float*)d_out;
    const int nCh = in_sizes[0] / kL;                 // 256 channels
    const int nBlk = nCh * kTilesPerCh;               // 2048 blocks (8|2048)

    hipLaunchKernelGGL(pink_tile, dim3(nBlk), dim3(kThr), 0, stream,
                       white, pink, nBlk);
}